// Round 5
// baseline (173.379 us; speedup 1.0000x reference)
//
#include <hip/hip_runtime.h>

// Problem constants
constexpr int IN_C  = 256;
constexpr int MID   = 32;
constexpr int OUT_C = 128;
constexpr int NR    = 512;
constexpr int NL    = 256;
constexpr int M     = 4;
constexpr long ROW_STRIDE = (long)(NR + NL) * OUT_C;   // 768*128 = 98304

// ---- workspace layout ----
// f32 region (float offsets)
constexpr long WS_PR4 = 0;                               // [4][512][32]   (rec proj, slice-major)
constexpr long WS_PL4 = WS_PR4 + 4L * NR * MID;          // [4][4][256][32] (lig proj [s][m][j][y])
constexpr long WS_F32_END = WS_PL4 + 4L * M * NL * MID;  // 196608 floats
// bf16 region (ushort offsets into ws)
constexpr long BF_LRR = 2 * WS_F32_END;                  // [512][32]  r_ri
constexpr long BF_LRL = BF_LRR + (long)NR * MID;         // [512][32]  r_li
constexpr long BF_LLR = BF_LRL + (long)NR * MID;         // [512][32]  r_lj
constexpr long BF_LLL = BF_LLR + (long)NR * MID;         // [256][128] l_li gathered [i][m*32+x]
constexpr long BF_TRR = BF_LLL + (long)NL * M * MID;     // [512][128][32]  T[j][o][k]
constexpr long BF_TRL = BF_TRR + (long)NR * OUT_C * MID; // [256][128][32]
constexpr long BF_TLR = BF_TRL + (long)NL * OUT_C * MID; // [256][128][32]
constexpr long BF_TLL = BF_TLR + (long)NL * OUT_C * MID; // [256][128][128]

typedef __bf16 bf16x8 __attribute__((ext_vector_type(8)));
typedef float  f32x4  __attribute__((ext_vector_type(4)));

__device__ inline unsigned short f2bf(float f) {
    unsigned int u = __float_as_uint(f);
    u = (u + 0x7fffu + ((u >> 16) & 1u)) >> 16;   // round-to-nearest-even
    return (unsigned short)u;
}

// ---------------------------------------------------------------------------
// K1: LayerNorm + projection. One block per row (512 rec + 1024 lig rows).
// ---------------------------------------------------------------------------
__global__ __launch_bounds__(256) void ln_proj_kernel(
    const float* __restrict__ rec, const float* __restrict__ lig,
    const float* __restrict__ rg, const float* __restrict__ rb,
    const float* __restrict__ lg, const float* __restrict__ lb,
    const float* __restrict__ Wr, const float* __restrict__ br,
    const float* __restrict__ Wl, const float* __restrict__ bl,
    float* __restrict__ ws)
{
    int row = blockIdx.x;
    bool isRec = (row < NR);
    const float *X, *g, *bvec, *W, *bias;
    float* P4;
    long slice_stride;
    int prow;
    if (isRec) {
        X = rec + (long)row * IN_C; g = rg; bvec = rb; W = Wr; bias = br;
        P4 = ws + WS_PR4; slice_stride = (long)NR * MID; prow = row;
    } else {
        int rl_ = row - NR;                       // m*256 + j
        X = lig + (long)rl_ * IN_C; g = lg; bvec = lb; W = Wl; bias = bl;
        P4 = ws + WS_PL4; slice_stride = (long)M * NL * MID; prow = rl_;
    }

    __shared__ __align__(16) float xn[IN_C];
    __shared__ float red[8];
    __shared__ float musig[2];
    __shared__ float part[256];

    int tid = threadIdx.x;
    float x = X[tid];
    float s = x, s2 = x * x;
    #pragma unroll
    for (int off = 32; off > 0; off >>= 1) {
        s  += __shfl_down(s,  off, 64);
        s2 += __shfl_down(s2, off, 64);
    }
    int wid = tid >> 6;
    if ((tid & 63) == 0) { red[wid] = s; red[4 + wid] = s2; }
    __syncthreads();
    if (tid == 0) {
        float sum  = red[0] + red[1] + red[2] + red[3];
        float sum2 = red[4] + red[5] + red[6] + red[7];
        float mu  = sum * (1.f / IN_C);
        float var = sum2 * (1.f / IN_C) - mu * mu;
        musig[0] = mu;
        musig[1] = rsqrtf(var + 1e-5f);
    }
    __syncthreads();
    float mu = musig[0], rs = musig[1];
    xn[tid] = (x - mu) * rs * g[tid] + bvec[tid];
    __syncthreads();

    // projection: 128 outputs, 2 threads each (half dots)
    int c = tid & 127, h = tid >> 7;
    const float* wrow = W + (long)c * IN_C + h * 128;
    const float* xp   = xn + h * 128;
    float acc = 0.f;
    #pragma unroll
    for (int k = 0; k < 128; k += 4) {
        float4 w4 = *(const float4*)(wrow + k);
        float4 x4 = *(const float4*)(xp + k);
        acc += w4.x * x4.x + w4.y * x4.y + w4.z * x4.z + w4.w * x4.w;
    }
    part[tid] = acc;
    __syncthreads();
    if (tid < 128) {
        float val = part[tid] + part[tid + 128] + bias[tid];
        int slice = tid & 3, xi = tid >> 2;
        P4[(long)slice * slice_stride + (long)prow * MID + xi] = val;

        unsigned short hb = f2bf(val);
        unsigned short* wsb = (unsigned short*)ws;
        if (isRec) {
            if (slice == 0)      wsb[BF_LRR + (long)prow * 32 + xi] = hb;   // r_ri
            else if (slice == 2) wsb[BF_LRL + (long)prow * 32 + xi] = hb;   // r_li
            else if (slice == 3) wsb[BF_LLR + (long)prow * 32 + xi] = hb;   // r_lj
        } else {
            if (slice == 2)      // l_li -> L_ll[i][m*32+x]
                wsb[BF_LLL + (long)(prow & 255) * 128 + (prow >> 8) * 32 + xi] = hb;
        }
    }
}

// ---------------------------------------------------------------------------
// K3: T[j][o][k] (bf16) = scale * sum_y W[o,x,y] * V[j,y]   (k = x, or m*32+x for ll)
// ---------------------------------------------------------------------------
__global__ __launch_bounds__(256) void build_t_kernel(
    const float* __restrict__ Wrr, const float* __restrict__ Wrl,
    const float* __restrict__ Wlr, const float* __restrict__ Wll,
    float* __restrict__ ws)
{
    unsigned short* wsb = (unsigned short*)ws;
    const float* V4 = ws + WS_PL4;   // [s][m][j][y]
    int bid = blockIdx.x;
    const float* W;
    unsigned short* T;
    float scale = 1.f;
    int mode, jt, cc, mm = 0, K;
    if (bid < 64)       { mode = 0; W = Wrr; T = wsb + BF_TRR; int r = bid;       jt = r >> 2; cc = r & 3; K = 32; }
    else if (bid < 96)  { mode = 1; W = Wrl; T = wsb + BF_TRL; int r = bid - 64;  jt = r >> 2; cc = r & 3; K = 32; }
    else if (bid < 128) { mode = 2; W = Wlr; T = wsb + BF_TLR; int r = bid - 96;  jt = r >> 2; cc = r & 3; K = 32; }
    else                { mode = 3; W = Wll; T = wsb + BF_TLL; int r = bid - 128; mm = r >> 5; r &= 31;
                          jt = r >> 2; cc = r & 3; K = 128; scale = 0.25f; }
    int j0 = jt * 32;

    __shared__ __align__(16) float v[32][32];
    int tid = threadIdx.x;
    for (int f = tid; f < 1024; f += 256) {
        int jl = f >> 5, y = f & 31;
        float val;
        if (mode == 0) {
            val = ws[WS_PR4 + 1L * NR * MID + (long)(j0 + jl) * MID + y];        // r_rj
        } else if (mode == 3) {
            val = V4[3L * M * NL * MID + (long)mm * NL * MID + (long)(j0 + jl) * MID + y]; // l_lj[m]
        } else {
            int sl = (mode == 1) ? 1 : 0;                                        // l_rj / l_ri
            const float* p = V4 + (long)sl * M * NL * MID + (long)(j0 + jl) * MID + y;
            val = 0.25f * (p[0] + p[NL * MID] + p[2L * NL * MID] + p[3L * NL * MID]);
        }
        v[jl][y] = val;
    }
    __syncthreads();

    int koff = (mode == 3) ? mm * 32 : 0;
    long jstride = (long)K * 128;
    #pragma unroll
    for (int pp = 0; pp < 2; ++pp) {
        int cpair = cc * 1024 + pp * 512 + tid * 2;  // c = o*32 + x, x even
        int o = cpair >> 5, x = cpair & 31;
        float wa[32], wb[32];
        const float4* wp = (const float4*)(W + (long)o * 1024 + x * 32);
        #pragma unroll
        for (int t4 = 0; t4 < 8; ++t4) {
            ((float4*)wa)[t4] = wp[t4];
            ((float4*)wb)[t4] = wp[t4 + 8];
        }
        long obase = (long)o * K + koff + x;
        for (int jl = 0; jl < 32; ++jl) {
            float accA = 0.f, accB = 0.f;
            #pragma unroll
            for (int y4 = 0; y4 < 8; ++y4) {
                float4 vv = *(const float4*)&v[jl][y4 * 4];
                accA += wa[y4*4+0]*vv.x + wa[y4*4+1]*vv.y + wa[y4*4+2]*vv.z + wa[y4*4+3]*vv.w;
                accB += wb[y4*4+0]*vv.x + wb[y4*4+1]*vv.y + wb[y4*4+2]*vv.z + wb[y4*4+3]*vv.w;
            }
            unsigned int pk = (unsigned int)f2bf(accA * scale)
                            | ((unsigned int)f2bf(accB * scale) << 16);
            *(unsigned int*)(T + (long)(j0 + jl) * jstride + obase) = pk;
        }
    }
}

// ---------------------------------------------------------------------------
// K4: MFMA epilogue with per-wave j-loop.
// out(i,j,o) = bias[o] + sum_k L[i,k]*T[j,o,k]  (operand-swapped: D reg axis = o)
// Block = (quadrant, i-tile of 128, window of JB=8 consecutive j).
// Each wave: 32 i rows, L fragments hoisted into registers, loops 8 j ->
// per i-row 8 x 512 B j-consecutive stores (4 KB merged in L2 before eviction).
// Grid 576 = 8 XCDs x (32 rr + 16 rl + 16 lr + 8 ll) -- identical mix per XCD.
// ---------------------------------------------------------------------------
template<int K>
__device__ inline void epi_tile(const unsigned short* __restrict__ L,
                                const unsigned short* __restrict__ T0,
                                const float* __restrict__ bias,
                                float* __restrict__ ob,
                                long jstr, long istr,
                                int i0w, int lrow, int lk)
{
    constexpr int NK = K / 32;
    bf16x8 bl0[NK], bl1[NK];
    #pragma unroll
    for (int ks = 0; ks < NK; ++ks) {
        int kb = ks * 32 + lk * 8;
        bl0[ks] = *(const bf16x8*)(L + (long)(i0w + lrow) * K + kb);
        bl1[ks] = *(const bf16x8*)(L + (long)(i0w + 16 + lrow) * K + kb);
    }
    for (int jj = 0; jj < 8; ++jj) {
        const unsigned short* T = T0 + (long)jj * K * 128;
        f32x4 acc[2][8];
        #pragma unroll
        for (int of = 0; of < 8; ++of) {
            f32x4 b4 = *(const f32x4*)(bias + of * 16 + lk * 4);
            acc[0][of] = b4; acc[1][of] = b4;
        }
        #pragma unroll
        for (int ks = 0; ks < NK; ++ks) {
            int kb = ks * 32 + lk * 8;
            #pragma unroll
            for (int of = 0; of < 8; ++of) {
                bf16x8 a = *(const bf16x8*)(T + (long)(of * 16 + lrow) * K + kb);
                acc[0][of] = __builtin_amdgcn_mfma_f32_16x16x32_bf16(a, bl0[ks], acc[0][of], 0, 0, 0);
                acc[1][of] = __builtin_amdgcn_mfma_f32_16x16x32_bf16(a, bl1[ks], acc[1][of], 0, 0, 0);
            }
        }
        float* obase = ob + (long)jj * jstr + (long)lk * 4;
        #pragma unroll
        for (int fi = 0; fi < 2; ++fi) {
            long ibase = (long)(i0w + fi * 16 + lrow) * istr;
            #pragma unroll
            for (int of = 0; of < 8; ++of) {
                *(f32x4*)(obase + ibase + of * 16) = acc[fi][of];
            }
        }
    }
}

__global__ __launch_bounds__(256) void epilogue_kernel(
    const float* __restrict__ ws, float* __restrict__ out,
    const float* __restrict__ brr, const float* __restrict__ brl,
    const float* __restrict__ blr, const float* __restrict__ bll)
{
    const unsigned short* wsb = (const unsigned short*)ws;
    int bid = blockIdx.x;
    int x = bid & 7;      // XCD (dispatch round-robin heuristic; perf-only)
    int r = bid >> 3;     // 0..71 within XCD

    const unsigned short *L, *T0;
    const float* bias;
    float* ob;
    long istr, jstr;
    int j0, it, quadK;
    if (r < 32) {               // rr: 4 it x 8 jt, j window 64
        it = r >> 3; j0 = x * 64 + (r & 7) * 8; quadK = 32;
        L = wsb + BF_LRR; T0 = wsb + BF_TRR + (long)j0 * 4096; bias = brr;
        ob = out; jstr = 128; istr = ROW_STRIDE;
    } else if (r < 48) {        // rl: 4 it x 4 jt, j window 32
        int w = r - 32; it = w >> 2; j0 = x * 32 + (w & 3) * 8; quadK = 32;
        L = wsb + BF_LRL; T0 = wsb + BF_TRL + (long)j0 * 4096; bias = brl;
        ob = out + (long)NR * OUT_C; jstr = 128; istr = ROW_STRIDE;
    } else if (r < 64) {        // lr: rows NR+j (lig), cols i (rec); 4 it x 4 jt
        int w = r - 48; it = w >> 2; j0 = x * 32 + (w & 3) * 8; quadK = 32;
        L = wsb + BF_LLR; T0 = wsb + BF_TLR + (long)j0 * 4096; bias = blr;
        ob = out + (long)NR * ROW_STRIDE; jstr = ROW_STRIDE; istr = 128;
    } else {                    // ll: 2 it x 4 jt, K=128
        int w = r - 64; it = w >> 2; j0 = x * 32 + (w & 3) * 8; quadK = 128;
        L = wsb + BF_LLL; T0 = wsb + BF_TLL + (long)j0 * 16384; bias = bll;
        ob = out + (long)NR * ROW_STRIDE + (long)NR * OUT_C; jstr = 128; istr = ROW_STRIDE;
    }

    int tid = threadIdx.x;
    int wv = tid >> 6, l = tid & 63;
    int lrow = l & 15, lk = l >> 4;
    int i0w = it * 128 + wv * 32;

    float* obj = ob + (long)j0 * jstr;
    if (quadK == 32)
        epi_tile<32>(L, T0, bias, obj, jstr, istr, i0w, lrow, lk);
    else
        epi_tile<128>(L, T0, bias, obj, jstr, istr, i0w, lrow, lk);
}

extern "C" void kernel_launch(void* const* d_in, const int* in_sizes, int n_in,
                              void* d_out, int out_size, void* d_ws, size_t ws_size,
                              hipStream_t stream)
{
    (void)in_sizes; (void)n_in; (void)out_size; (void)ws_size;
    const float* rec = (const float*)d_in[0];
    const float* lig = (const float*)d_in[1];
    // d_in[2] = pw_rep: shape-only, never read (all 4 quadrants are overwritten)
    const float* rg  = (const float*)d_in[3];
    const float* rb  = (const float*)d_in[4];
    const float* lg  = (const float*)d_in[5];
    const float* lb  = (const float*)d_in[6];
    const float* Wr  = (const float*)d_in[7];
    const float* br  = (const float*)d_in[8];
    const float* Wl  = (const float*)d_in[9];
    const float* bl  = (const float*)d_in[10];
    const float* Wrr = (const float*)d_in[11];
    const float* brr = (const float*)d_in[12];
    const float* Wrl = (const float*)d_in[13];
    const float* brl = (const float*)d_in[14];
    const float* Wlr = (const float*)d_in[15];
    const float* blr = (const float*)d_in[16];
    const float* Wll = (const float*)d_in[17];
    const float* bll = (const float*)d_in[18];
    float* out = (float*)d_out;
    float* ws  = (float*)d_ws;

    hipLaunchKernelGGL(ln_proj_kernel, dim3(NR + M * NL), dim3(256), 0, stream,
                       rec, lig, rg, rb, lg, lb, Wr, br, Wl, bl, ws);
    hipLaunchKernelGGL(build_t_kernel, dim3(256), dim3(256), 0, stream,
                       Wrr, Wrl, Wlr, Wll, ws);
    hipLaunchKernelGGL(epilogue_kernel, dim3(576), dim3(256), 0, stream,
                       ws, out, brr, brl, blr, bll);
}

// Round 6
// 116.051 us; speedup vs baseline: 1.4940x; 1.4940x over previous
//
#include <hip/hip_runtime.h>

// Problem constants
constexpr int IN_C  = 256;
constexpr int MID   = 32;
constexpr int OUT_C = 128;
constexpr int NR    = 512;
constexpr int NL    = 256;
constexpr int M     = 4;
constexpr long ROW_STRIDE = (long)(NR + NL) * OUT_C;   // 768*128 = 98304

// ---- workspace layout ----
// f32 region (float offsets)
constexpr long WS_PR4 = 0;                               // [4][512][32]   (rec proj, slice-major)
constexpr long WS_PL4 = WS_PR4 + 4L * NR * MID;          // [4][4][256][32] (lig proj [s][m][j][y])
constexpr long WS_F32_END = WS_PL4 + 4L * M * NL * MID;  // 196608 floats
// bf16 region (ushort offsets into ws)
constexpr long BF_LRR = 2 * WS_F32_END;                  // [512][32]  r_ri
constexpr long BF_LRL = BF_LRR + (long)NR * MID;         // [512][32]  r_li
constexpr long BF_LLR = BF_LRL + (long)NR * MID;         // [512][32]  r_lj
constexpr long BF_LLL = BF_LLR + (long)NR * MID;         // [256][128] l_li gathered [i][m*32+x]
constexpr long BF_TRR = BF_LLL + (long)NL * M * MID;     // [512][128][32]  T[j][o][k]
constexpr long BF_TRL = BF_TRR + (long)NR * OUT_C * MID; // [256][128][32]
constexpr long BF_TLR = BF_TRL + (long)NL * OUT_C * MID; // [256][128][32]
constexpr long BF_TLL = BF_TLR + (long)NL * OUT_C * MID; // [256][128][128]

typedef __bf16 bf16x8 __attribute__((ext_vector_type(8)));
typedef float  f32x4  __attribute__((ext_vector_type(4)));

__device__ inline unsigned short f2bf(float f) {
    unsigned int u = __float_as_uint(f);
    u = (u + 0x7fffu + ((u >> 16) & 1u)) >> 16;   // round-to-nearest-even
    return (unsigned short)u;
}

// ---------------------------------------------------------------------------
// K1: LayerNorm + projection. One block per row (512 rec + 1024 lig rows).
// ---------------------------------------------------------------------------
__global__ __launch_bounds__(256) void ln_proj_kernel(
    const float* __restrict__ rec, const float* __restrict__ lig,
    const float* __restrict__ rg, const float* __restrict__ rb,
    const float* __restrict__ lg, const float* __restrict__ lb,
    const float* __restrict__ Wr, const float* __restrict__ br,
    const float* __restrict__ Wl, const float* __restrict__ bl,
    float* __restrict__ ws)
{
    int row = blockIdx.x;
    bool isRec = (row < NR);
    const float *X, *g, *bvec, *W, *bias;
    float* P4;
    long slice_stride;
    int prow;
    if (isRec) {
        X = rec + (long)row * IN_C; g = rg; bvec = rb; W = Wr; bias = br;
        P4 = ws + WS_PR4; slice_stride = (long)NR * MID; prow = row;
    } else {
        int rl_ = row - NR;                       // m*256 + j
        X = lig + (long)rl_ * IN_C; g = lg; bvec = lb; W = Wl; bias = bl;
        P4 = ws + WS_PL4; slice_stride = (long)M * NL * MID; prow = rl_;
    }

    __shared__ __align__(16) float xn[IN_C];
    __shared__ float red[8];
    __shared__ float musig[2];
    __shared__ float part[256];

    int tid = threadIdx.x;
    float x = X[tid];
    float s = x, s2 = x * x;
    #pragma unroll
    for (int off = 32; off > 0; off >>= 1) {
        s  += __shfl_down(s,  off, 64);
        s2 += __shfl_down(s2, off, 64);
    }
    int wid = tid >> 6;
    if ((tid & 63) == 0) { red[wid] = s; red[4 + wid] = s2; }
    __syncthreads();
    if (tid == 0) {
        float sum  = red[0] + red[1] + red[2] + red[3];
        float sum2 = red[4] + red[5] + red[6] + red[7];
        float mu  = sum * (1.f / IN_C);
        float var = sum2 * (1.f / IN_C) - mu * mu;
        musig[0] = mu;
        musig[1] = rsqrtf(var + 1e-5f);
    }
    __syncthreads();
    float mu = musig[0], rs = musig[1];
    xn[tid] = (x - mu) * rs * g[tid] + bvec[tid];
    __syncthreads();

    // projection: 128 outputs, 2 threads each (half dots)
    int c = tid & 127, h = tid >> 7;
    const float* wrow = W + (long)c * IN_C + h * 128;
    const float* xp   = xn + h * 128;
    float acc = 0.f;
    #pragma unroll
    for (int k = 0; k < 128; k += 4) {
        float4 w4 = *(const float4*)(wrow + k);
        float4 x4 = *(const float4*)(xp + k);
        acc += w4.x * x4.x + w4.y * x4.y + w4.z * x4.z + w4.w * x4.w;
    }
    part[tid] = acc;
    __syncthreads();
    if (tid < 128) {
        float val = part[tid] + part[tid + 128] + bias[tid];
        int slice = tid & 3, xi = tid >> 2;
        P4[(long)slice * slice_stride + (long)prow * MID + xi] = val;

        unsigned short hb = f2bf(val);
        unsigned short* wsb = (unsigned short*)ws;
        if (isRec) {
            if (slice == 0)      wsb[BF_LRR + (long)prow * 32 + xi] = hb;   // r_ri
            else if (slice == 2) wsb[BF_LRL + (long)prow * 32 + xi] = hb;   // r_li
            else if (slice == 3) wsb[BF_LLR + (long)prow * 32 + xi] = hb;   // r_lj
        } else {
            if (slice == 2)      // l_li -> L_ll[i][m*32+x]
                wsb[BF_LLL + (long)(prow & 255) * 128 + (prow >> 8) * 32 + xi] = hb;
        }
    }
}

// ---------------------------------------------------------------------------
// K3: T[j][o][k] (bf16) = scale * sum_y W[o,x,y] * V[j,y]   (k = x, or m*32+x for ll)
// ---------------------------------------------------------------------------
__global__ __launch_bounds__(256) void build_t_kernel(
    const float* __restrict__ Wrr, const float* __restrict__ Wrl,
    const float* __restrict__ Wlr, const float* __restrict__ Wll,
    float* __restrict__ ws)
{
    unsigned short* wsb = (unsigned short*)ws;
    const float* V4 = ws + WS_PL4;   // [s][m][j][y]
    int bid = blockIdx.x;
    const float* W;
    unsigned short* T;
    float scale = 1.f;
    int mode, jt, cc, mm = 0, K;
    if (bid < 64)       { mode = 0; W = Wrr; T = wsb + BF_TRR; int r = bid;       jt = r >> 2; cc = r & 3; K = 32; }
    else if (bid < 96)  { mode = 1; W = Wrl; T = wsb + BF_TRL; int r = bid - 64;  jt = r >> 2; cc = r & 3; K = 32; }
    else if (bid < 128) { mode = 2; W = Wlr; T = wsb + BF_TLR; int r = bid - 96;  jt = r >> 2; cc = r & 3; K = 32; }
    else                { mode = 3; W = Wll; T = wsb + BF_TLL; int r = bid - 128; mm = r >> 5; r &= 31;
                          jt = r >> 2; cc = r & 3; K = 128; scale = 0.25f; }
    int j0 = jt * 32;

    __shared__ __align__(16) float v[32][32];
    int tid = threadIdx.x;
    for (int f = tid; f < 1024; f += 256) {
        int jl = f >> 5, y = f & 31;
        float val;
        if (mode == 0) {
            val = ws[WS_PR4 + 1L * NR * MID + (long)(j0 + jl) * MID + y];        // r_rj
        } else if (mode == 3) {
            val = V4[3L * M * NL * MID + (long)mm * NL * MID + (long)(j0 + jl) * MID + y]; // l_lj[m]
        } else {
            int sl = (mode == 1) ? 1 : 0;                                        // l_rj / l_ri
            const float* p = V4 + (long)sl * M * NL * MID + (long)(j0 + jl) * MID + y;
            val = 0.25f * (p[0] + p[NL * MID] + p[2L * NL * MID] + p[3L * NL * MID]);
        }
        v[jl][y] = val;
    }
    __syncthreads();

    int koff = (mode == 3) ? mm * 32 : 0;
    long jstride = (long)K * 128;
    #pragma unroll
    for (int pp = 0; pp < 2; ++pp) {
        int cpair = cc * 1024 + pp * 512 + tid * 2;  // c = o*32 + x, x even
        int o = cpair >> 5, x = cpair & 31;
        float wa[32], wb[32];
        const float4* wp = (const float4*)(W + (long)o * 1024 + x * 32);
        #pragma unroll
        for (int t4 = 0; t4 < 8; ++t4) {
            ((float4*)wa)[t4] = wp[t4];
            ((float4*)wb)[t4] = wp[t4 + 8];
        }
        long obase = (long)o * K + koff + x;
        for (int jl = 0; jl < 32; ++jl) {
            float accA = 0.f, accB = 0.f;
            #pragma unroll
            for (int y4 = 0; y4 < 8; ++y4) {
                float4 vv = *(const float4*)&v[jl][y4 * 4];
                accA += wa[y4*4+0]*vv.x + wa[y4*4+1]*vv.y + wa[y4*4+2]*vv.z + wa[y4*4+3]*vv.w;
                accB += wb[y4*4+0]*vv.x + wb[y4*4+1]*vv.y + wb[y4*4+2]*vv.z + wb[y4*4+3]*vv.w;
            }
            unsigned int pk = (unsigned int)f2bf(accA * scale)
                            | ((unsigned int)f2bf(accB * scale) << 16);
            *(unsigned int*)(T + (long)(j0 + jl) * jstride + obase) = pk;
        }
    }
}

// ---------------------------------------------------------------------------
// K4: MFMA epilogue, wave-per-j.
// out(i,j,o) = bias[o] + sum_k L[i,k]*T[j,o,k]  (operand-swapped: D reg axis = o)
// Block = (quadrant, 32-i tile, window of 4 consecutive j); wave wv takes j0+wv.
// All 4 waves store the SAME 32 i-rows at 4 ADJACENT j simultaneously ->
// 2 KB j-contiguous runs per i-row guaranteed within one CU's store window.
// Grid 4608 = 8 XCDs x (256 rr + 128 rl + 128 lr + 64 ll), j-window fastest.
// ---------------------------------------------------------------------------
template<int K>
__device__ inline void epi_wave(const unsigned short* __restrict__ L,
                                const unsigned short* __restrict__ T,
                                const float* __restrict__ bias,
                                float* __restrict__ obrow,
                                long istr, int i0, int lrow, int lk)
{
    constexpr int NK = K / 32;
    bf16x8 bl0[NK], bl1[NK];
    #pragma unroll
    for (int ks = 0; ks < NK; ++ks) {
        int kb = ks * 32 + lk * 8;
        bl0[ks] = *(const bf16x8*)(L + (long)(i0 + lrow) * K + kb);
        bl1[ks] = *(const bf16x8*)(L + (long)(i0 + 16 + lrow) * K + kb);
    }
    f32x4 acc[2][8];
    #pragma unroll
    for (int of = 0; of < 8; ++of) {
        f32x4 b4 = *(const f32x4*)(bias + of * 16 + lk * 4);
        acc[0][of] = b4; acc[1][of] = b4;
    }
    #pragma unroll
    for (int ks = 0; ks < NK; ++ks) {
        int kb = ks * 32 + lk * 8;
        #pragma unroll
        for (int of = 0; of < 8; ++of) {
            bf16x8 a = *(const bf16x8*)(T + (long)(of * 16 + lrow) * K + kb);
            acc[0][of] = __builtin_amdgcn_mfma_f32_16x16x32_bf16(a, bl0[ks], acc[0][of], 0, 0, 0);
            acc[1][of] = __builtin_amdgcn_mfma_f32_16x16x32_bf16(a, bl1[ks], acc[1][of], 0, 0, 0);
        }
    }
    // D: col = l&15 -> i_local, reg row = lk*4+r -> o_local. float4 along o.
    float* obase = obrow + (long)lk * 4;
    #pragma unroll
    for (int fi = 0; fi < 2; ++fi) {
        long ibase = (long)(i0 + fi * 16 + lrow) * istr;
        #pragma unroll
        for (int of = 0; of < 8; ++of) {
            *(f32x4*)(obase + ibase + of * 16) = acc[fi][of];
        }
    }
}

__global__ __launch_bounds__(256) void epilogue_kernel(
    const float* __restrict__ ws, float* __restrict__ out,
    const float* __restrict__ brr, const float* __restrict__ brl,
    const float* __restrict__ blr, const float* __restrict__ bll)
{
    const unsigned short* wsb = (const unsigned short*)ws;
    int bid = blockIdx.x;
    int x = bid & 7;      // XCD (dispatch round-robin heuristic; perf-only)
    int r = bid >> 3;     // 0..575 within XCD

    const unsigned short *L, *Tq;
    const float* bias;
    float* ob;
    long istr, jstr;
    int j0, i0, quadK;
    if (r < 256) {               // rr: 16 it x 16 jw (4 j each), j window 64/XCD
        int jw = r & 15, it = r >> 4;
        j0 = x * 64 + jw * 4; i0 = it * 32; quadK = 32;
        L = wsb + BF_LRR; Tq = wsb + BF_TRR; bias = brr;
        ob = out; jstr = 128; istr = ROW_STRIDE;
    } else if (r < 384) {        // rl: 16 it x 8 jw, j window 32/XCD
        int w = r - 256; int jw = w & 7, it = w >> 3;
        j0 = x * 32 + jw * 4; i0 = it * 32; quadK = 32;
        L = wsb + BF_LRL; Tq = wsb + BF_TRL; bias = brl;
        ob = out + (long)NR * OUT_C; jstr = 128; istr = ROW_STRIDE;
    } else if (r < 512) {        // lr: rows NR+j (lig), cols i (rec); 16 it x 8 jw
        int w = r - 384; int jw = w & 7, it = w >> 3;
        j0 = x * 32 + jw * 4; i0 = it * 32; quadK = 32;
        L = wsb + BF_LLR; Tq = wsb + BF_TLR; bias = blr;
        ob = out + (long)NR * ROW_STRIDE; jstr = ROW_STRIDE; istr = 128;
    } else {                     // ll: 8 it x 8 jw, K=128
        int w = r - 512; int jw = w & 7, it = w >> 3;
        j0 = x * 32 + jw * 4; i0 = it * 32; quadK = 128;
        L = wsb + BF_LLL; Tq = wsb + BF_TLL; bias = bll;
        ob = out + (long)NR * ROW_STRIDE + (long)NR * OUT_C; jstr = 128; istr = ROW_STRIDE;
    }

    int tid = threadIdx.x;
    int wv = tid >> 6, l = tid & 63;
    int lrow = l & 15, lk = l >> 4;
    int j = j0 + wv;

    if (quadK == 32) {
        const unsigned short* T = Tq + (long)j * 4096;
        epi_wave<32>(L, T, bias, ob + (long)j * jstr, istr, i0, lrow, lk);
    } else {
        const unsigned short* T = Tq + (long)j * 16384;
        epi_wave<128>(L, T, bias, ob + (long)j * jstr, istr, i0, lrow, lk);
    }
}

extern "C" void kernel_launch(void* const* d_in, const int* in_sizes, int n_in,
                              void* d_out, int out_size, void* d_ws, size_t ws_size,
                              hipStream_t stream)
{
    (void)in_sizes; (void)n_in; (void)out_size; (void)ws_size;
    const float* rec = (const float*)d_in[0];
    const float* lig = (const float*)d_in[1];
    // d_in[2] = pw_rep: shape-only, never read (all 4 quadrants are overwritten)
    const float* rg  = (const float*)d_in[3];
    const float* rb  = (const float*)d_in[4];
    const float* lg  = (const float*)d_in[5];
    const float* lb  = (const float*)d_in[6];
    const float* Wr  = (const float*)d_in[7];
    const float* br  = (const float*)d_in[8];
    const float* Wl  = (const float*)d_in[9];
    const float* bl  = (const float*)d_in[10];
    const float* Wrr = (const float*)d_in[11];
    const float* brr = (const float*)d_in[12];
    const float* Wrl = (const float*)d_in[13];
    const float* brl = (const float*)d_in[14];
    const float* Wlr = (const float*)d_in[15];
    const float* blr = (const float*)d_in[16];
    const float* Wll = (const float*)d_in[17];
    const float* bll = (const float*)d_in[18];
    float* out = (float*)d_out;
    float* ws  = (float*)d_ws;

    hipLaunchKernelGGL(ln_proj_kernel, dim3(NR + M * NL), dim3(256), 0, stream,
                       rec, lig, rg, rb, lg, lb, Wr, br, Wl, bl, ws);
    hipLaunchKernelGGL(build_t_kernel, dim3(256), dim3(256), 0, stream,
                       Wrr, Wrl, Wlr, Wll, ws);
    hipLaunchKernelGGL(epilogue_kernel, dim3(4608), dim3(256), 0, stream,
                       ws, out, brr, brl, blr, bll);
}

// Round 7
// 113.564 us; speedup vs baseline: 1.5267x; 1.0219x over previous
//
#include <hip/hip_runtime.h>

// Problem constants
constexpr int IN_C  = 256;
constexpr int MID   = 32;
constexpr int OUT_C = 128;
constexpr int NR    = 512;
constexpr int NL    = 256;
constexpr int M     = 4;
constexpr long ROW_STRIDE = (long)(NR + NL) * OUT_C;   // 768*128 = 98304

// ---- workspace layout ----
// f32 region (float offsets)
constexpr long WS_PR4 = 0;                               // [4][512][32]   (rec proj, slice-major)
constexpr long WS_PL4 = WS_PR4 + 4L * NR * MID;          // [4][4][256][32] (lig proj [s][m][j][y])
constexpr long WS_F32_END = WS_PL4 + 4L * M * NL * MID;  // 196608 floats
// bf16 region (ushort offsets into ws)
constexpr long BF_LRR = 2 * WS_F32_END;                  // [512][32]  r_ri
constexpr long BF_LRL = BF_LRR + (long)NR * MID;         // [512][32]  r_li
constexpr long BF_LLR = BF_LRL + (long)NR * MID;         // [512][32]  r_lj
constexpr long BF_LLL = BF_LLR + (long)NR * MID;         // [256][128] l_li gathered [i][m*32+x]
constexpr long BF_TRR = BF_LLL + (long)NL * M * MID;     // [512][128][32]  T[j][o][k]
constexpr long BF_TRL = BF_TRR + (long)NR * OUT_C * MID; // [256][128][32]
constexpr long BF_TLR = BF_TRL + (long)NL * OUT_C * MID; // [256][128][32]
constexpr long BF_TLL = BF_TLR + (long)NL * OUT_C * MID; // [256][128][128]

typedef __bf16 bf16x8 __attribute__((ext_vector_type(8)));
typedef float  f32x4  __attribute__((ext_vector_type(4)));

__device__ inline unsigned short f2bf(float f) {
    unsigned int u = __float_as_uint(f);
    u = (u + 0x7fffu + ((u >> 16) & 1u)) >> 16;   // round-to-nearest-even
    return (unsigned short)u;
}

// ---------------------------------------------------------------------------
// K1: LayerNorm + projection. One block per row (512 rec + 1024 lig rows).
// ---------------------------------------------------------------------------
__global__ __launch_bounds__(256) void ln_proj_kernel(
    const float* __restrict__ rec, const float* __restrict__ lig,
    const float* __restrict__ rg, const float* __restrict__ rb,
    const float* __restrict__ lg, const float* __restrict__ lb,
    const float* __restrict__ Wr, const float* __restrict__ br,
    const float* __restrict__ Wl, const float* __restrict__ bl,
    float* __restrict__ ws)
{
    int row = blockIdx.x;
    bool isRec = (row < NR);
    const float *X, *g, *bvec, *W, *bias;
    float* P4;
    long slice_stride;
    int prow;
    if (isRec) {
        X = rec + (long)row * IN_C; g = rg; bvec = rb; W = Wr; bias = br;
        P4 = ws + WS_PR4; slice_stride = (long)NR * MID; prow = row;
    } else {
        int rl_ = row - NR;                       // m*256 + j
        X = lig + (long)rl_ * IN_C; g = lg; bvec = lb; W = Wl; bias = bl;
        P4 = ws + WS_PL4; slice_stride = (long)M * NL * MID; prow = rl_;
    }

    __shared__ __align__(16) float xn[IN_C];
    __shared__ float red[8];
    __shared__ float musig[2];
    __shared__ float part[256];

    int tid = threadIdx.x;
    float x = X[tid];
    float s = x, s2 = x * x;
    #pragma unroll
    for (int off = 32; off > 0; off >>= 1) {
        s  += __shfl_down(s,  off, 64);
        s2 += __shfl_down(s2, off, 64);
    }
    int wid = tid >> 6;
    if ((tid & 63) == 0) { red[wid] = s; red[4 + wid] = s2; }
    __syncthreads();
    if (tid == 0) {
        float sum  = red[0] + red[1] + red[2] + red[3];
        float sum2 = red[4] + red[5] + red[6] + red[7];
        float mu  = sum * (1.f / IN_C);
        float var = sum2 * (1.f / IN_C) - mu * mu;
        musig[0] = mu;
        musig[1] = rsqrtf(var + 1e-5f);
    }
    __syncthreads();
    float mu = musig[0], rs = musig[1];
    xn[tid] = (x - mu) * rs * g[tid] + bvec[tid];
    __syncthreads();

    // projection: 128 outputs, 2 threads each (half dots)
    int c = tid & 127, h = tid >> 7;
    const float* wrow = W + (long)c * IN_C + h * 128;
    const float* xp   = xn + h * 128;
    float acc = 0.f;
    #pragma unroll
    for (int k = 0; k < 128; k += 4) {
        float4 w4 = *(const float4*)(wrow + k);
        float4 x4 = *(const float4*)(xp + k);
        acc += w4.x * x4.x + w4.y * x4.y + w4.z * x4.z + w4.w * x4.w;
    }
    part[tid] = acc;
    __syncthreads();
    if (tid < 128) {
        float val = part[tid] + part[tid + 128] + bias[tid];
        int slice = tid & 3, xi = tid >> 2;
        P4[(long)slice * slice_stride + (long)prow * MID + xi] = val;

        unsigned short hb = f2bf(val);
        unsigned short* wsb = (unsigned short*)ws;
        if (isRec) {
            if (slice == 0)      wsb[BF_LRR + (long)prow * 32 + xi] = hb;   // r_ri
            else if (slice == 2) wsb[BF_LRL + (long)prow * 32 + xi] = hb;   // r_li
            else if (slice == 3) wsb[BF_LLR + (long)prow * 32 + xi] = hb;   // r_lj
        } else {
            if (slice == 2)      // l_li -> L_ll[i][m*32+x]
                wsb[BF_LLL + (long)(prow & 255) * 128 + (prow >> 8) * 32 + xi] = hb;
        }
    }
}

// ---------------------------------------------------------------------------
// K3: T[j][o][k] (bf16) = scale * sum_y W[o,x,y] * V[j,y]   (k = x, or m*32+x for ll)
// ---------------------------------------------------------------------------
__global__ __launch_bounds__(256) void build_t_kernel(
    const float* __restrict__ Wrr, const float* __restrict__ Wrl,
    const float* __restrict__ Wlr, const float* __restrict__ Wll,
    float* __restrict__ ws)
{
    unsigned short* wsb = (unsigned short*)ws;
    const float* V4 = ws + WS_PL4;   // [s][m][j][y]
    int bid = blockIdx.x;
    const float* W;
    unsigned short* T;
    float scale = 1.f;
    int mode, jt, cc, mm = 0, K;
    if (bid < 64)       { mode = 0; W = Wrr; T = wsb + BF_TRR; int r = bid;       jt = r >> 2; cc = r & 3; K = 32; }
    else if (bid < 96)  { mode = 1; W = Wrl; T = wsb + BF_TRL; int r = bid - 64;  jt = r >> 2; cc = r & 3; K = 32; }
    else if (bid < 128) { mode = 2; W = Wlr; T = wsb + BF_TLR; int r = bid - 96;  jt = r >> 2; cc = r & 3; K = 32; }
    else                { mode = 3; W = Wll; T = wsb + BF_TLL; int r = bid - 128; mm = r >> 5; r &= 31;
                          jt = r >> 2; cc = r & 3; K = 128; scale = 0.25f; }
    int j0 = jt * 32;

    __shared__ __align__(16) float v[32][32];
    int tid = threadIdx.x;
    for (int f = tid; f < 1024; f += 256) {
        int jl = f >> 5, y = f & 31;
        float val;
        if (mode == 0) {
            val = ws[WS_PR4 + 1L * NR * MID + (long)(j0 + jl) * MID + y];        // r_rj
        } else if (mode == 3) {
            val = V4[3L * M * NL * MID + (long)mm * NL * MID + (long)(j0 + jl) * MID + y]; // l_lj[m]
        } else {
            int sl = (mode == 1) ? 1 : 0;                                        // l_rj / l_ri
            const float* p = V4 + (long)sl * M * NL * MID + (long)(j0 + jl) * MID + y;
            val = 0.25f * (p[0] + p[NL * MID] + p[2L * NL * MID] + p[3L * NL * MID]);
        }
        v[jl][y] = val;
    }
    __syncthreads();

    int koff = (mode == 3) ? mm * 32 : 0;
    long jstride = (long)K * 128;
    #pragma unroll
    for (int pp = 0; pp < 2; ++pp) {
        int cpair = cc * 1024 + pp * 512 + tid * 2;  // c = o*32 + x, x even
        int o = cpair >> 5, x = cpair & 31;
        float wa[32], wb[32];
        const float4* wp = (const float4*)(W + (long)o * 1024 + x * 32);
        #pragma unroll
        for (int t4 = 0; t4 < 8; ++t4) {
            ((float4*)wa)[t4] = wp[t4];
            ((float4*)wb)[t4] = wp[t4 + 8];
        }
        long obase = (long)o * K + koff + x;
        for (int jl = 0; jl < 32; ++jl) {
            float accA = 0.f, accB = 0.f;
            #pragma unroll
            for (int y4 = 0; y4 < 8; ++y4) {
                float4 vv = *(const float4*)&v[jl][y4 * 4];
                accA += wa[y4*4+0]*vv.x + wa[y4*4+1]*vv.y + wa[y4*4+2]*vv.z + wa[y4*4+3]*vv.w;
                accB += wb[y4*4+0]*vv.x + wb[y4*4+1]*vv.y + wb[y4*4+2]*vv.z + wb[y4*4+3]*vv.w;
            }
            unsigned int pk = (unsigned int)f2bf(accA * scale)
                            | ((unsigned int)f2bf(accB * scale) << 16);
            *(unsigned int*)(T + (long)(j0 + jl) * jstride + obase) = pk;
        }
    }
}

// ---------------------------------------------------------------------------
// K4: MFMA epilogue, wave-per-j with inner i-chunk loop (T-reuse).
// out(i,j,o) = bias[o] + sum_k L[i,k]*T[j,o,k]  (operand-swapped: D reg axis = o)
// Block = (quadrant, 64-i tile, window of 4 consecutive j); wave wv owns j0+wv
// and loops ic=0,1 over two 32-i chunks (T[j] re-read while L2-hot).
// Cross-block T re-reads: rr 8 (was 16), rl/lr 8, ll 4 -> ~2x less L2-miss
// T traffic under the output write stream. Store pattern per i-row unchanged:
// 4 adjacent-j waves write 2 KB j-contiguous runs simultaneously.
// Grid 2304 = 8 XCDs x (128 rr + 64 rl + 64 lr + 32 ll), jw-fastest.
// ---------------------------------------------------------------------------
template<int K>
__device__ inline void epi_wave(const unsigned short* __restrict__ L,
                                const unsigned short* __restrict__ T,
                                const float* __restrict__ bias,
                                float* __restrict__ obrow,
                                long istr, int i0, int lrow, int lk)
{
    constexpr int NK = K / 32;
    bf16x8 bl0[NK], bl1[NK];
    #pragma unroll
    for (int ks = 0; ks < NK; ++ks) {
        int kb = ks * 32 + lk * 8;
        bl0[ks] = *(const bf16x8*)(L + (long)(i0 + lrow) * K + kb);
        bl1[ks] = *(const bf16x8*)(L + (long)(i0 + 16 + lrow) * K + kb);
    }
    f32x4 acc[2][8];
    #pragma unroll
    for (int of = 0; of < 8; ++of) {
        f32x4 b4 = *(const f32x4*)(bias + of * 16 + lk * 4);
        acc[0][of] = b4; acc[1][of] = b4;
    }
    #pragma unroll
    for (int ks = 0; ks < NK; ++ks) {
        int kb = ks * 32 + lk * 8;
        #pragma unroll
        for (int of = 0; of < 8; ++of) {
            bf16x8 a = *(const bf16x8*)(T + (long)(of * 16 + lrow) * K + kb);
            acc[0][of] = __builtin_amdgcn_mfma_f32_16x16x32_bf16(a, bl0[ks], acc[0][of], 0, 0, 0);
            acc[1][of] = __builtin_amdgcn_mfma_f32_16x16x32_bf16(a, bl1[ks], acc[1][of], 0, 0, 0);
        }
    }
    // D: col = l&15 -> i_local, reg row = lk*4+r -> o_local. float4 along o.
    float* obase = obrow + (long)lk * 4;
    #pragma unroll
    for (int fi = 0; fi < 2; ++fi) {
        long ibase = (long)(i0 + fi * 16 + lrow) * istr;
        #pragma unroll
        for (int of = 0; of < 8; ++of) {
            *(f32x4*)(obase + ibase + of * 16) = acc[fi][of];
        }
    }
}

__global__ __launch_bounds__(256) void epilogue_kernel(
    const float* __restrict__ ws, float* __restrict__ out,
    const float* __restrict__ brr, const float* __restrict__ brl,
    const float* __restrict__ blr, const float* __restrict__ bll)
{
    const unsigned short* wsb = (const unsigned short*)ws;
    int bid = blockIdx.x;
    int x = bid & 7;      // XCD (dispatch round-robin heuristic; perf-only)
    int r = bid >> 3;     // 0..287 within XCD

    const unsigned short *L, *Tq;
    const float* bias;
    float* ob;
    long istr, jstr;
    int j0, i0b, quadK;
    if (r < 128) {               // rr: 8 it x 16 jw (4 j each), j window 64/XCD
        int jw = r & 15, it = r >> 4;
        j0 = x * 64 + jw * 4; i0b = it * 64; quadK = 32;
        L = wsb + BF_LRR; Tq = wsb + BF_TRR; bias = brr;
        ob = out; jstr = 128; istr = ROW_STRIDE;
    } else if (r < 192) {        // rl: 8 it x 8 jw, j window 32/XCD
        int w = r - 128; int jw = w & 7, it = w >> 3;
        j0 = x * 32 + jw * 4; i0b = it * 64; quadK = 32;
        L = wsb + BF_LRL; Tq = wsb + BF_TRL; bias = brl;
        ob = out + (long)NR * OUT_C; jstr = 128; istr = ROW_STRIDE;
    } else if (r < 256) {        // lr: rows NR+j (lig), cols i (rec); 8 it x 8 jw
        int w = r - 192; int jw = w & 7, it = w >> 3;
        j0 = x * 32 + jw * 4; i0b = it * 64; quadK = 32;
        L = wsb + BF_LLR; Tq = wsb + BF_TLR; bias = blr;
        ob = out + (long)NR * ROW_STRIDE; jstr = ROW_STRIDE; istr = 128;
    } else {                     // ll: 4 it x 8 jw, K=128
        int w = r - 256; int jw = w & 7, it = w >> 3;
        j0 = x * 32 + jw * 4; i0b = it * 64; quadK = 128;
        L = wsb + BF_LLL; Tq = wsb + BF_TLL; bias = bll;
        ob = out + (long)NR * ROW_STRIDE + (long)NR * OUT_C; jstr = 128; istr = ROW_STRIDE;
    }

    int tid = threadIdx.x;
    int wv = tid >> 6, l = tid & 63;
    int lrow = l & 15, lk = l >> 4;
    int j = j0 + wv;

    if (quadK == 32) {
        const unsigned short* T = Tq + (long)j * 4096;
        float* obj = ob + (long)j * jstr;
        #pragma unroll
        for (int ic = 0; ic < 2; ++ic)
            epi_wave<32>(L, T, bias, obj, istr, i0b + ic * 32, lrow, lk);
    } else {
        const unsigned short* T = Tq + (long)j * 16384;
        float* obj = ob + (long)j * jstr;
        #pragma unroll
        for (int ic = 0; ic < 2; ++ic)
            epi_wave<128>(L, T, bias, obj, istr, i0b + ic * 32, lrow, lk);
    }
}

extern "C" void kernel_launch(void* const* d_in, const int* in_sizes, int n_in,
                              void* d_out, int out_size, void* d_ws, size_t ws_size,
                              hipStream_t stream)
{
    (void)in_sizes; (void)n_in; (void)out_size; (void)ws_size;
    const float* rec = (const float*)d_in[0];
    const float* lig = (const float*)d_in[1];
    // d_in[2] = pw_rep: shape-only, never read (all 4 quadrants are overwritten)
    const float* rg  = (const float*)d_in[3];
    const float* rb  = (const float*)d_in[4];
    const float* lg  = (const float*)d_in[5];
    const float* lb  = (const float*)d_in[6];
    const float* Wr  = (const float*)d_in[7];
    const float* br  = (const float*)d_in[8];
    const float* Wl  = (const float*)d_in[9];
    const float* bl  = (const float*)d_in[10];
    const float* Wrr = (const float*)d_in[11];
    const float* brr = (const float*)d_in[12];
    const float* Wrl = (const float*)d_in[13];
    const float* brl = (const float*)d_in[14];
    const float* Wlr = (const float*)d_in[15];
    const float* blr = (const float*)d_in[16];
    const float* Wll = (const float*)d_in[17];
    const float* bll = (const float*)d_in[18];
    float* out = (float*)d_out;
    float* ws  = (float*)d_ws;

    hipLaunchKernelGGL(ln_proj_kernel, dim3(NR + M * NL), dim3(256), 0, stream,
                       rec, lig, rg, rb, lg, lb, Wr, br, Wl, bl, ws);
    hipLaunchKernelGGL(build_t_kernel, dim3(256), dim3(256), 0, stream,
                       Wrr, Wrl, Wlr, Wll, ws);
    hipLaunchKernelGGL(epilogue_kernel, dim3(2304), dim3(256), 0, stream,
                       ws, out, brr, brl, blr, bll);
}